// Round 4
// baseline (483.471 us; speedup 1.0000x reference)
//
#include <hip/hip_runtime.h>
#include <cfloat>

#define TT 16
#define KK 512
#define DD 128
#define BT 128        // b-rows per block (z-resident)
#define KTILE 128     // k-rows per chunk
#define NKC 4         // KK / KTILE
#define PP 260        // floats per LDS row-pair: 256 data + 4 pad (1040 B)
#define N0 16777216   // 8192*16*128 (z_q_st)
#define N1 131072     // 8192*16     (tokens)

__device__ __forceinline__ void gl_lds16(const float* g, const float* l) {
  __builtin_amdgcn_global_load_lds(
      (const __attribute__((address_space(1))) void*)g,
      (__attribute__((address_space(3))) void*)l, 16, 0, 0);
}

// numpy pairwise-sum (n<=128: 8 strided accumulators + tree combine) of x^2
__device__ __forceinline__ float np_sum128_sq_f4(const float4* __restrict__ p) {
  float4 a = p[0], b = p[1];
  float r[8];
  r[0] = __fmul_rn(a.x, a.x); r[1] = __fmul_rn(a.y, a.y);
  r[2] = __fmul_rn(a.z, a.z); r[3] = __fmul_rn(a.w, a.w);
  r[4] = __fmul_rn(b.x, b.x); r[5] = __fmul_rn(b.y, b.y);
  r[6] = __fmul_rn(b.z, b.z); r[7] = __fmul_rn(b.w, b.w);
#pragma unroll
  for (int i = 1; i < 16; ++i) {
    a = p[2 * i]; b = p[2 * i + 1];
    r[0] = __fadd_rn(r[0], __fmul_rn(a.x, a.x));
    r[1] = __fadd_rn(r[1], __fmul_rn(a.y, a.y));
    r[2] = __fadd_rn(r[2], __fmul_rn(a.z, a.z));
    r[3] = __fadd_rn(r[3], __fmul_rn(a.w, a.w));
    r[4] = __fadd_rn(r[4], __fmul_rn(b.x, b.x));
    r[5] = __fadd_rn(r[5], __fmul_rn(b.y, b.y));
    r[6] = __fadd_rn(r[6], __fmul_rn(b.z, b.z));
    r[7] = __fadd_rn(r[7], __fmul_rn(b.w, b.w));
  }
  return __fadd_rn(__fadd_rn(__fadd_rn(r[0], r[1]), __fadd_rn(r[2], r[3])),
                   __fadd_rn(__fadd_rn(r[4], r[5]), __fadd_rn(r[6], r[7])));
}

__global__ __launch_bounds__(256, 1) void vq_main(
    const float* __restrict__ z_e, const float* __restrict__ cb,
    float* __restrict__ out, float* __restrict__ loss_part,
    int* __restrict__ used) {
  // pair-padded: row r lives at (r>>1)*PP + (r&1)*128 (+ d)
  __shared__ alignas(16) float z_s[64 * PP];   // 66560 B, resident all kernel
  __shared__ alignas(16) float c_s[64 * PP];   // 66560 B, per-chunk (reused for merge)
  __shared__ float A_s[BT];
  __shared__ float q_s[KTILE];
  __shared__ int   tok_s[BT];
  __shared__ float wred[4];

  const int tid  = threadIdx.x;
  const int lane = tid & 63;
  const int w    = tid >> 6;
  const int t    = blockIdx.y;
  const int b0   = blockIdx.x * BT;
  const int bt   = tid & 15;   // b rows: bt + 16*i
  const int kt   = tid >> 4;   // k rows: kt + 16*j

  // ---- prologue: DMA z tile (64 pairs) + c chunk 0 (64 pairs) ----
#pragma unroll
  for (int i = 0; i < 16; ++i) {
    int p = w * 16 + i;                       // pair index, wave-uniform
    int r = 2 * p + (lane >> 5);              // z rows not contiguous in global
    gl_lds16(z_e + ((size_t)(b0 + r) * TT + t) * DD + (lane & 31) * 4,
             z_s + p * PP);
  }
#pragma unroll
  for (int i = 0; i < 16; ++i) {
    int p = w * 16 + i;                       // c rows contiguous: 1024 B straight
    gl_lds16(cb + ((size_t)t * KK + 2 * p) * DD + lane * 4, c_s + p * PP);
  }
  __syncthreads();

  // ||z||^2 (np pairwise order) from global — just-fetched, L2-warm
  if (tid < BT)
    A_s[tid] = np_sum128_sq_f4(
        (const float4*)(z_e + ((size_t)(b0 + tid) * TT + t) * DD));

  float bestv[8];
  int   bestk[8];
#pragma unroll
  for (int i = 0; i < 8; ++i) { bestv[i] = FLT_MAX; bestk[i] = 0; }

  const int zbase = (bt >> 1) * PP + (bt & 1) * 128;
  const int cbase = (kt >> 1) * PP + (kt & 1) * 128;

#pragma unroll 1
  for (int kc = 0; kc < NKC; ++kc) {
    // VGPR prefetch of next chunk (issued ~8500 cyc before use)
    float4 pf[16];
    if (kc < NKC - 1) {
      const float4* src =
          (const float4*)(cb + ((size_t)t * KK + (kc + 1) * KTILE) * DD);
#pragma unroll
      for (int it = 0; it < 16; ++it) pf[it] = src[it * 256 + tid];
    }
    // ||c||^2 for current chunk (np order), global is L2-warm
    if (tid < KTILE)
      q_s[tid] = np_sum128_sq_f4(
          (const float4*)(cb + ((size_t)t * KK + kc * KTILE + tid) * DD));

    float acc[8][8];
#pragma unroll
    for (int i = 0; i < 8; ++i)
#pragma unroll
      for (int j = 0; j < 8; ++j) acc[i][j] = 0.0f;

#pragma unroll 2
    for (int d4 = 0; d4 < 32; ++d4) {
      float4 a[8], c[8];
#pragma unroll
      for (int i = 0; i < 8; ++i)
        a[i] = *(const float4*)(z_s + zbase + i * (8 * PP) + d4 * 4);
#pragma unroll
      for (int j = 0; j < 8; ++j)
        c[j] = *(const float4*)(c_s + cbase + j * (8 * PP) + d4 * 4);
#pragma unroll
      for (int i = 0; i < 8; ++i)
#pragma unroll
        for (int j = 0; j < 8; ++j) {
          float s = acc[i][j];
          s = __builtin_fmaf(a[i].x, c[j].x, s);
          s = __builtin_fmaf(a[i].y, c[j].y, s);
          s = __builtin_fmaf(a[i].z, c[j].z, s);
          s = __builtin_fmaf(a[i].w, c[j].w, s);
          acc[i][j] = s;
        }
    }
    __syncthreads();  // (A) compute done; q_s visible

    // distances (reference rounding); per-thread k strictly increasing
#pragma unroll
    for (int i = 0; i < 8; ++i) {
      float Ai = A_s[bt + 16 * i];
#pragma unroll
      for (int j = 0; j < 8; ++j) {
        float dist = __fadd_rn(__fsub_rn(Ai, __fmul_rn(2.0f, acc[i][j])),
                               q_s[kt + 16 * j]);
        if (dist < bestv[i]) {
          bestv[i] = dist;
          bestk[i] = kc * KTILE + kt + 16 * j;
        }
      }
    }

    if (kc < NKC - 1) {
      // commit prefetched chunk to LDS (pair-padded layout)
#pragma unroll
      for (int it = 0; it < 16; ++it) {
        int idx = it * 256 + tid;           // float4 index in 128x32 chunk
        int r = idx >> 5, cc = idx & 31;
        *(float4*)(c_s + (r >> 1) * PP + (r & 1) * 128 + cc * 4) = pf[it];
      }
      __syncthreads();  // (B) chunk kc+1 ready
    }
  }

  // ---- cross-thread argmin merge (reuse c_s as u64[BT][16]) ----
  unsigned long long* best_s = (unsigned long long*)c_s;
#pragma unroll
  for (int i = 0; i < 8; ++i)
    best_s[(bt + 16 * i) * 16 + kt] =
        ((unsigned long long)__float_as_uint(bestv[i]) << 32) | (unsigned)bestk[i];
  __syncthreads();
  if (tid < BT) {
    unsigned long long bb = best_s[tid * 16];
#pragma unroll
    for (int g = 1; g < 16; ++g) {
      unsigned long long v = best_s[tid * 16 + g];
      bb = (v < bb) ? v : bb;
    }
    const int tok = (int)(bb & 0xffffffffULL);
    tok_s[tid] = tok;
    out[(size_t)N0 + (size_t)(b0 + tid) * TT + t] = (float)tok;
    atomicOr(&used[t * KK + tok], 1);
  }
  __syncthreads();

  // ---- epilogue: z_q_st = z + (c - z); z from LDS, c from global (L2) ----
  float lsum = 0.0f;
#pragma unroll
  for (int it = 0; it < 16; ++it) {
    int idx = tid + it * 256;
    int r = idx >> 5, c = idx & 31;
    int k = tok_s[r];
    float4 cv = *(const float4*)(cb + ((size_t)t * KK + k) * DD + c * 4);
    float4 zv = *(const float4*)(z_s + (r >> 1) * PP + (r & 1) * 128 + c * 4);
    float4 o;
    o.x = __fadd_rn(zv.x, __fsub_rn(cv.x, zv.x));
    o.y = __fadd_rn(zv.y, __fsub_rn(cv.y, zv.y));
    o.z = __fadd_rn(zv.z, __fsub_rn(cv.z, zv.z));
    o.w = __fadd_rn(zv.w, __fsub_rn(cv.w, zv.w));
    *(float4*)(out + ((size_t)(b0 + r) * TT + t) * DD + c * 4) = o;
    float dx = zv.x - cv.x, dy = zv.y - cv.y, dz = zv.z - cv.z, dw = zv.w - cv.w;
    lsum += dx * dx + dy * dy + dz * dz + dw * dw;
  }
#pragma unroll
  for (int off = 32; off > 0; off >>= 1) lsum += __shfl_down(lsum, off, 64);
  if ((tid & 63) == 0) wred[tid >> 6] = lsum;
  __syncthreads();
  if (tid == 0)
    loss_part[blockIdx.y * 64 + blockIdx.x] =
        wred[0] + wred[1] + wred[2] + wred[3];
}

__global__ void vq_final(const float* __restrict__ loss_part,
                         const int* __restrict__ used, float* __restrict__ out) {
  __shared__ float partf[4];
  __shared__ int   parti[4];
  int tid = threadIdx.x;
  float ls = 0.0f;
  for (int i = tid; i < 1024; i += 256) ls += loss_part[i];
  int c = 0;
  for (int i = tid; i < TT * KK; i += 256) c += used[i];
#pragma unroll
  for (int off = 32; off > 0; off >>= 1) {
    ls += __shfl_down(ls, off, 64);
    c  += __shfl_down(c, off, 64);
  }
  if ((tid & 63) == 0) { partf[tid >> 6] = ls; parti[tid >> 6] = c; }
  __syncthreads();
  if (tid == 0) {
    float lt = partf[0] + partf[1] + partf[2] + partf[3];
    int   tot = parti[0] + parti[1] + parti[2] + parti[3];
    out[(size_t)N0 + N1]     = 0.25f * lt / 16777216.0f;  // BETA * mean
    out[(size_t)N0 + N1 + 1] = (float)tot / 8192.0f;      // utilization
  }
}

extern "C" void kernel_launch(void* const* d_in, const int* in_sizes, int n_in,
                              void* d_out, int out_size, void* d_ws, size_t ws_size,
                              hipStream_t stream) {
  const float* z_e = (const float*)d_in[0];
  const float* cb  = (const float*)d_in[1];
  float* out = (float*)d_out;
  float* loss_part = (float*)d_ws;                  // 1024 floats
  int*   used      = (int*)((char*)d_ws + 4096);    // 8192 ints
  hipMemsetAsync(d_ws, 0, 4096 + TT * KK * sizeof(int), stream);
  vq_main<<<dim3(8192 / BT, TT), 256, 0, stream>>>(z_e, cb, out, loss_part, used);
  vq_final<<<1, 256, 0, stream>>>(loss_part, used, out);
}

// Round 5
// 466.042 us; speedup vs baseline: 1.0374x; 1.0374x over previous
//
#include <hip/hip_runtime.h>
#include <cfloat>

#define TT 16
#define KK 512
#define DD 128
#define BT 128        // b-rows per block (z resident in LDS, full d)
#define KTILE 64      // k-rows per DMA chunk (double-buffered)
#define NKC 8         // KK / KTILE
#define PP 260        // floats per LDS row-pair: 256 data + 4 pad (1040 B)
#define N0 16777216   // 8192*16*128 (z_q_st)
#define N1 131072     // 8192*16     (tokens)

__device__ __forceinline__ void gl_lds16(const float* g, const float* l) {
  __builtin_amdgcn_global_load_lds(
      (const __attribute__((address_space(1))) void*)g,
      (__attribute__((address_space(3))) void*)l, 16, 0, 0);
}

// numpy pairwise-sum (n<=128: 8 strided accumulators + tree combine) of x^2
__device__ __forceinline__ float np_sum128_sq_f4(const float4* __restrict__ p) {
  float4 a = p[0], b = p[1];
  float r[8];
  r[0] = __fmul_rn(a.x, a.x); r[1] = __fmul_rn(a.y, a.y);
  r[2] = __fmul_rn(a.z, a.z); r[3] = __fmul_rn(a.w, a.w);
  r[4] = __fmul_rn(b.x, b.x); r[5] = __fmul_rn(b.y, b.y);
  r[6] = __fmul_rn(b.z, b.z); r[7] = __fmul_rn(b.w, b.w);
#pragma unroll
  for (int i = 1; i < 16; ++i) {
    a = p[2 * i]; b = p[2 * i + 1];
    r[0] = __fadd_rn(r[0], __fmul_rn(a.x, a.x));
    r[1] = __fadd_rn(r[1], __fmul_rn(a.y, a.y));
    r[2] = __fadd_rn(r[2], __fmul_rn(a.z, a.z));
    r[3] = __fadd_rn(r[3], __fmul_rn(a.w, a.w));
    r[4] = __fadd_rn(r[4], __fmul_rn(b.x, b.x));
    r[5] = __fadd_rn(r[5], __fmul_rn(b.y, b.y));
    r[6] = __fadd_rn(r[6], __fmul_rn(b.z, b.z));
    r[7] = __fadd_rn(r[7], __fmul_rn(b.w, b.w));
  }
  return __fadd_rn(__fadd_rn(__fadd_rn(r[0], r[1]), __fadd_rn(r[2], r[3])),
                   __fadd_rn(__fadd_rn(r[4], r[5]), __fadd_rn(r[6], r[7])));
}

__global__ __launch_bounds__(256, 1) void vq_main(
    const float* __restrict__ z_e, const float* __restrict__ cb,
    float* __restrict__ out, float* __restrict__ loss_part,
    int* __restrict__ used) {
  // pair-padded: row r at (r>>1)*PP + (r&1)*128
  __shared__ alignas(16) float z_s[64 * PP];        // 66560 B, resident
  __shared__ alignas(16) float c_s[2 * 32 * PP];    // 66560 B, dbuf (reused: merge)
  __shared__ float q_all[KK];                       // 2 KB
  __shared__ float A_s[BT];
  __shared__ int   tok_s[BT];
  __shared__ float wred[4];

  const int tid  = threadIdx.x;
  const int lane = tid & 63;
  const int w    = tid >> 6;
  const int t    = blockIdx.y;
  const int b0   = blockIdx.x * BT;
  const int bt   = tid & 15;   // b rows: bt + 16*i, i<8
  const int kt   = tid >> 4;   // k rows: kt + 16*j, j<4 (within chunk)

  // ---- prologue: DMA z tile (64 pairs) + c chunk 0 (32 pairs) ----
#pragma unroll
  for (int i = 0; i < 16; ++i) {
    int p = w * 16 + i;  // wave-uniform pair index
    gl_lds16(z_e + ((size_t)(b0 + 2 * p + (lane >> 5)) * TT + t) * DD +
                 (lane & 31) * 4,
             z_s + p * PP);
  }
#pragma unroll
  for (int i = 0; i < 8; ++i) {
    int p = w * 8 + i;
    gl_lds16(cb + ((size_t)t * KK + 2 * p) * DD + lane * 4, c_s + p * PP);
  }

  // ||c||^2 for all 512 rows (np pairwise order), overlapped with DMA
  q_all[tid] = np_sum128_sq_f4((const float4*)(cb + ((size_t)t * KK + tid) * DD));
  q_all[tid + 256] =
      np_sum128_sq_f4((const float4*)(cb + ((size_t)t * KK + tid + 256) * DD));
  // ||z||^2 for this block's rows
  if (tid < BT)
    A_s[tid] = np_sum128_sq_f4(
        (const float4*)(z_e + ((size_t)(b0 + tid) * TT + t) * DD));
  __syncthreads();

  float Areg[8];
#pragma unroll
  for (int i = 0; i < 8; ++i) Areg[i] = A_s[bt + 16 * i];

  float bestv[8];
  int   bestk[8];
#pragma unroll
  for (int i = 0; i < 8; ++i) { bestv[i] = FLT_MAX; bestk[i] = 0; }

  const int zbase = (bt >> 1) * PP + (bt & 1) * 128;
  const int cbase = (kt >> 1) * PP + (kt & 1) * 128;

#pragma unroll 1
  for (int kc = 0; kc < NKC; ++kc) {
    const float* cbuf = c_s + (kc & 1) * (32 * PP);
    if (kc < NKC - 1) {
      float* nbuf = c_s + ((kc + 1) & 1) * (32 * PP);
#pragma unroll
      for (int i = 0; i < 8; ++i) {
        int p = w * 8 + i;
        gl_lds16(cb + ((size_t)t * KK + (kc + 1) * KTILE + 2 * p) * DD + lane * 4,
                 nbuf + p * PP);
      }
    }

    float acc[8][4];
#pragma unroll
    for (int i = 0; i < 8; ++i)
#pragma unroll
      for (int j = 0; j < 4; ++j) acc[i][j] = 0.0f;

#pragma unroll 2
    for (int d4 = 0; d4 < 32; ++d4) {
      float4 a[8], c[4];
#pragma unroll
      for (int i = 0; i < 8; ++i)
        a[i] = *(const float4*)(z_s + zbase + i * (8 * PP) + d4 * 4);
#pragma unroll
      for (int j = 0; j < 4; ++j)
        c[j] = *(const float4*)(cbuf + cbase + j * (8 * PP) + d4 * 4);
#pragma unroll
      for (int i = 0; i < 8; ++i)
#pragma unroll
        for (int j = 0; j < 4; ++j) {
          float s = acc[i][j];
          s = __builtin_fmaf(a[i].x, c[j].x, s);
          s = __builtin_fmaf(a[i].y, c[j].y, s);
          s = __builtin_fmaf(a[i].z, c[j].z, s);
          s = __builtin_fmaf(a[i].w, c[j].w, s);
          acc[i][j] = s;
        }
    }

    // distances (reference rounding); per-thread k strictly increasing
#pragma unroll
    for (int i = 0; i < 8; ++i) {
#pragma unroll
      for (int j = 0; j < 4; ++j) {
        int kk = kc * KTILE + kt + 16 * j;
        float dist =
            __fadd_rn(__fsub_rn(Areg[i], __fmul_rn(2.0f, acc[i][j])), q_all[kk]);
        if (dist < bestv[i]) { bestv[i] = dist; bestk[i] = kk; }
      }
    }
    __syncthreads();  // all reads of cbuf done; DMA for kc+1 drained (long done)
  }

  // ---- cross-thread argmin merge (reuse c_s as u64[BT][16]) ----
  unsigned long long* best_s = (unsigned long long*)c_s;
#pragma unroll
  for (int i = 0; i < 8; ++i)
    best_s[(bt + 16 * i) * 16 + kt] =
        ((unsigned long long)__float_as_uint(bestv[i]) << 32) | (unsigned)bestk[i];
  __syncthreads();
  if (tid < BT) {
    unsigned long long bb = best_s[tid * 16];
#pragma unroll
    for (int g = 1; g < 16; ++g) {
      unsigned long long v = best_s[tid * 16 + g];
      bb = (v < bb) ? v : bb;
    }
    const int tok = (int)(bb & 0xffffffffULL);
    tok_s[tid] = tok;
    out[(size_t)N0 + (size_t)(b0 + tid) * TT + t] = (float)tok;
    atomicOr(&used[t * KK + tok], 1);
  }
  __syncthreads();

  // ---- epilogue: z_q_st = z + (c - z); z from LDS, c from global (L2) ----
  float lsum = 0.0f;
#pragma unroll
  for (int it = 0; it < 16; ++it) {
    int idx = tid + it * 256;
    int r = idx >> 5, c = idx & 31;
    int k = tok_s[r];
    float4 cv = *(const float4*)(cb + ((size_t)t * KK + k) * DD + c * 4);
    float4 zv = *(const float4*)(z_s + (r >> 1) * PP + (r & 1) * 128 + c * 4);
    float4 o;
    o.x = __fadd_rn(zv.x, __fsub_rn(cv.x, zv.x));
    o.y = __fadd_rn(zv.y, __fsub_rn(cv.y, zv.y));
    o.z = __fadd_rn(zv.z, __fsub_rn(cv.z, zv.z));
    o.w = __fadd_rn(zv.w, __fsub_rn(cv.w, zv.w));
    *(float4*)(out + ((size_t)(b0 + r) * TT + t) * DD + c * 4) = o;
    float dx = zv.x - cv.x, dy = zv.y - cv.y, dz = zv.z - cv.z, dw = zv.w - cv.w;
    lsum += dx * dx + dy * dy + dz * dz + dw * dw;
  }
#pragma unroll
  for (int off = 32; off > 0; off >>= 1) lsum += __shfl_down(lsum, off, 64);
  if ((tid & 63) == 0) wred[tid >> 6] = lsum;
  __syncthreads();
  if (tid == 0)
    loss_part[blockIdx.y * 64 + blockIdx.x] =
        wred[0] + wred[1] + wred[2] + wred[3];
}

__global__ void vq_final(const float* __restrict__ loss_part,
                         const int* __restrict__ used, float* __restrict__ out) {
  __shared__ float partf[4];
  __shared__ int   parti[4];
  int tid = threadIdx.x;
  float ls = 0.0f;
  for (int i = tid; i < 1024; i += 256) ls += loss_part[i];
  int c = 0;
  for (int i = tid; i < TT * KK; i += 256) c += used[i];
#pragma unroll
  for (int off = 32; off > 0; off >>= 1) {
    ls += __shfl_down(ls, off, 64);
    c  += __shfl_down(c, off, 64);
  }
  if ((tid & 63) == 0) { partf[tid >> 6] = ls; parti[tid >> 6] = c; }
  __syncthreads();
  if (tid == 0) {
    float lt = partf[0] + partf[1] + partf[2] + partf[3];
    int   tot = parti[0] + parti[1] + parti[2] + parti[3];
    out[(size_t)N0 + N1]     = 0.25f * lt / 16777216.0f;  // BETA * mean
    out[(size_t)N0 + N1 + 1] = (float)tot / 8192.0f;      // utilization
  }
}

extern "C" void kernel_launch(void* const* d_in, const int* in_sizes, int n_in,
                              void* d_out, int out_size, void* d_ws, size_t ws_size,
                              hipStream_t stream) {
  const float* z_e = (const float*)d_in[0];
  const float* cb  = (const float*)d_in[1];
  float* out = (float*)d_out;
  float* loss_part = (float*)d_ws;                  // 1024 floats
  int*   used      = (int*)((char*)d_ws + 4096);    // 8192 ints
  hipMemsetAsync(d_ws, 0, 4096 + TT * KK * sizeof(int), stream);
  vq_main<<<dim3(8192 / BT, TT), 256, 0, stream>>>(z_e, cb, out, loss_part, used);
  vq_final<<<1, 256, 0, stream>>>(loss_part, used, out);
}